// Round 2
// baseline (765.002 us; speedup 1.0000x reference)
//
#include <hip/hip_runtime.h>
#include <math.h>

typedef _Float16 f16_t;
typedef _Float16 f16x8 __attribute__((ext_vector_type(8)));
typedef _Float16 f16x4 __attribute__((ext_vector_type(4)));
typedef float f32x4 __attribute__((ext_vector_type(4)));

#define XSTRIDE 136  // f16 units; 272B row: 16B-aligned rows, uniform LDS bank coverage for b128

// Convert W1 [256][128] and W2 [256][256] fp32 -> fp16 into d_ws, k-chunk-major with
// a 16B-group swizzle baked in so that a lane-linear global_load_lds copy yields
// conflict-free B-fragment ds_read_b128s.
// Chunk kc = [256 n][32 k] (8192 f16 = 16KB). Element (n, k=kc*32+q*8+j) stored at
// chunkBase + n*32 + (q ^ ((n>>1)&3))*8 + j.  W1: chunks 0..3 at 0; W2: chunks 0..7 at 32768.
__global__ void wconv(const float* __restrict__ W1, const float* __restrict__ W2,
                      f16_t* __restrict__ o) {
  int idx = blockIdx.x * 256 + threadIdx.x;  // 0..65535
  if (idx < 32768) {
    int n = idx >> 7, k = idx & 127;
    int kc = k >> 5, q = (k >> 3) & 3, j = k & 7;
    int qp = q ^ ((n >> 1) & 3);
    o[kc * 8192 + n * 32 + qp * 8 + j] = (f16_t)W1[idx];
  }
  {
    int n = idx >> 8, k = idx & 255;
    int kc = k >> 5, q = (k >> 3) & 3, j = k & 7;
    int qp = q ^ ((n >> 1) & 3);
    o[32768 + kc * 8192 + n * 32 + qp * 8 + j] = (f16_t)W2[idx];
  }
}

__device__ __forceinline__ void stage16(const f16_t* g, f16_t* l) {
  __builtin_amdgcn_global_load_lds(
      (const __attribute__((address_space(1))) void*)g,
      (__attribute__((address_space(3))) void*)l, 16, 0, 0);
}

// Fused: gather-product -> GEMM1+LN+ReLU -> GEMM2 (K-split) +LN+ReLU -> dot(W3)+sigmoid.
// 512 threads = 8 waves as 2 wave-rows (M=64) x 4 wave-cols (N=64); M-tile 128 edges.
// Static LDS 56320 B -> 2 blocks/CU.
__global__ __launch_bounds__(512, 4) void fused_mlp(
    const float* __restrict__ h,
    const int* __restrict__ src,
    const int* __restrict__ dst,
    const f16_t* __restrict__ wks,
    const float* __restrict__ b1, const float* __restrict__ g1, const float* __restrict__ be1,
    const float* __restrict__ b2, const float* __restrict__ g2, const float* __restrict__ be2,
    const float* __restrict__ w3, const float* __restrict__ b3,
    float* __restrict__ out, int E, int nrows) {
  __shared__ __attribute__((aligned(16))) f16_t xbuf[128 * XSTRIDE];  // x0, then x1 k-halves
  __shared__ __attribute__((aligned(16))) f16_t wb[8192];             // one 16KB weight chunk
  __shared__ float ssum[512];
  __shared__ float ssq[512];
  __shared__ float smean[128];
  __shared__ float srstd[128];

  const int t = threadIdx.x;
  const int ebase = blockIdx.x * 128;

  auto stage_chunk = [&](int off) {  // off in f16 elements; copies 16KB wks->wb lane-linear
    const f16_t* g0 = wks + off + t * 8;
    stage16(g0, wb + t * 8);
    stage16(g0 + 4096, wb + 4096 + t * 8);
  };

  // kick off W1 chunk 0 before the gather so it overlaps the global h reads
  stage_chunk(0);

  // ---------- gather: x0[m][k] = h[src][k]*h[dst][k] (fp16) ----------
  {
    const int m = t >> 2;
    const int kq = (t & 3) * 32;
    const int e = ebase + m;
    f16_t* xrow = xbuf + m * XSTRIDE + kq;
    if (e < E) {
      int si = src[e], di = dst[e];
      si = ((unsigned)si < (unsigned)nrows) ? si : 0;  // safety clamp
      di = ((unsigned)di < (unsigned)nrows) ? di : 0;
      const float* hs = h + (long long)si * 128 + kq;
      const float* hd = h + (long long)di * 128 + kq;
#pragma unroll
      for (int i = 0; i < 4; ++i) {
        const float4 a0 = *(const float4*)(hs + i * 8);
        const float4 a1 = *(const float4*)(hs + i * 8 + 4);
        const float4 c0 = *(const float4*)(hd + i * 8);
        const float4 c1 = *(const float4*)(hd + i * 8 + 4);
        f16x8 v;
        v[0] = (f16_t)(a0.x * c0.x); v[1] = (f16_t)(a0.y * c0.y);
        v[2] = (f16_t)(a0.z * c0.z); v[3] = (f16_t)(a0.w * c0.w);
        v[4] = (f16_t)(a1.x * c1.x); v[5] = (f16_t)(a1.y * c1.y);
        v[6] = (f16_t)(a1.z * c1.z); v[7] = (f16_t)(a1.w * c1.w);
        *(f16x8*)(xrow + i * 8) = v;
      }
    } else {
      f16x8 z = {};
#pragma unroll
      for (int i = 0; i < 4; ++i) *(f16x8*)(xrow + i * 8) = z;
    }
  }
  __syncthreads();  // x0 ready; W1 chunk0 drained (vmcnt(0) before barrier)

  const int lane = t & 63;
  const int wave = t >> 6;
  const int wm = wave >> 2;  // 0..1
  const int wn = wave & 3;   // 0..3
  const int c = lane & 15;
  const int q = lane >> 4;
  const int qp = q ^ ((c >> 1) & 3);          // B-frag swizzle (per-lane constant)
  const int arow0 = wm * 64 + c;
  const int bcol0 = wn * 64 + c;
  const int aoff = arow0 * XSTRIDE + q * 8;   // + ms*16*XSTRIDE + klocal
  const int boff = bcol0 * 32 + qp * 8;       // + ns*512

  auto gstep = [&](f32x4 (&A)[4][4], int klocal) {
    f16x8 af[4], bf[4];
#pragma unroll
    for (int ms = 0; ms < 4; ++ms)
      af[ms] = *(const f16x8*)(xbuf + aoff + ms * (16 * XSTRIDE) + klocal);
#pragma unroll
    for (int ns = 0; ns < 4; ++ns)
      bf[ns] = *(const f16x8*)(wb + boff + ns * 512);
#pragma unroll
    for (int ms = 0; ms < 4; ++ms)
#pragma unroll
      for (int ns = 0; ns < 4; ++ns)
        A[ms][ns] = __builtin_amdgcn_mfma_f32_16x16x32_f16(af[ms], bf[ns], A[ms][ns], 0, 0, 0);
  };

  f32x4 acc[4][4];
#pragma unroll
  for (int ms = 0; ms < 4; ++ms)
#pragma unroll
    for (int ns = 0; ns < 4; ++ns) acc[ms][ns] = (f32x4){0.f, 0.f, 0.f, 0.f};

  // ---------- GEMM1: x0 @ W1^T -> [128,256] ----------
#pragma unroll
  for (int kc = 0; kc < 4; ++kc) {
    gstep(acc, kc * 32);
    __syncthreads();                       // wb readers done (kc==3: also x0 readers done)
    if (kc < 3) {
      stage_chunk((kc + 1) * 8192);
      __syncthreads();                     // chunk resident
    }
  }
  stage_chunk(32768);                      // W2 chunk 0 in flight during LN1

  // ---------- LN1 ----------
  float bias[4], gg[4], bb[4];
#pragma unroll
  for (int ns = 0; ns < 4; ++ns) {
    int n = bcol0 + ns * 16;
    bias[ns] = b1[n]; gg[ns] = g1[n]; bb[ns] = be1[n];
  }
#pragma unroll
  for (int ms = 0; ms < 4; ++ms) {
#pragma unroll
    for (int r = 0; r < 4; ++r) {
      float s = 0.f, sq = 0.f;
#pragma unroll
      for (int ns = 0; ns < 4; ++ns) {
        float v = acc[ms][ns][r] + bias[ns];
        acc[ms][ns][r] = v;
        s += v; sq += v * v;
      }
#pragma unroll
      for (int off = 1; off < 16; off <<= 1) {
        s += __shfl_xor(s, off, 64);
        sq += __shfl_xor(sq, off, 64);
      }
      if (c == 0) {
        int row = wm * 64 + ms * 16 + q * 4 + r;
        ssum[wn * 128 + row] = s;
        ssq[wn * 128 + row] = sq;
      }
    }
  }
  __syncthreads();
  if (t < 128) {
    float s = ssum[t] + ssum[128 + t] + ssum[256 + t] + ssum[384 + t];
    float sq = ssq[t] + ssq[128 + t] + ssq[256 + t] + ssq[384 + t];
    float mu = s * (1.f / 256.f);
    float var = sq * (1.f / 256.f) - mu * mu;
    smean[t] = mu;
    srstd[t] = rsqrtf(var + 1e-5f);
  }
  __syncthreads();

  // normalize + relu -> packed fp16 (32 VGPRs); waves wn<2 write K-half A (cols 0..127)
  f16x4 hv[4][4];
#pragma unroll
  for (int ms = 0; ms < 4; ++ms) {
#pragma unroll
    for (int r = 0; r < 4; ++r) {
      int row = wm * 64 + ms * 16 + q * 4 + r;
      float mu = smean[row], rs = srstd[row];
#pragma unroll
      for (int ns = 0; ns < 4; ++ns) {
        float v = (acc[ms][ns][r] - mu) * rs * gg[ns] + bb[ns];
        hv[ms][ns][r] = (f16_t)fmaxf(v, 0.f);
      }
    }
  }
  if (wn < 2) {
#pragma unroll
    for (int ms = 0; ms < 4; ++ms)
#pragma unroll
      for (int r = 0; r < 4; ++r) {
        int row = wm * 64 + ms * 16 + q * 4 + r;
#pragma unroll
        for (int ns = 0; ns < 4; ++ns)
          xbuf[row * XSTRIDE + wn * 64 + ns * 16 + c] = hv[ms][ns][r];
      }
  }
  __syncthreads();  // x1 half-A visible; W2 chunk0 drained

  // ---------- GEMM2 (K-split): pass A k=0..127, pass B k=128..255 ----------
  f32x4 acc2[4][4];
#pragma unroll
  for (int ms = 0; ms < 4; ++ms)
#pragma unroll
    for (int ns = 0; ns < 4; ++ns) acc2[ms][ns] = (f32x4){0.f, 0.f, 0.f, 0.f};

#pragma unroll
  for (int kc = 0; kc < 4; ++kc) {
    gstep(acc2, kc * 32);
    __syncthreads();
    if (kc < 3) {
      stage_chunk(32768 + (kc + 1) * 8192);
      __syncthreads();
    }
  }
  stage_chunk(32768 + 4 * 8192);           // W2 chunk 4
  if (wn >= 2) {                           // write K-half B (cols 128..255 -> local 0..127)
#pragma unroll
    for (int ms = 0; ms < 4; ++ms)
#pragma unroll
      for (int r = 0; r < 4; ++r) {
        int row = wm * 64 + ms * 16 + q * 4 + r;
#pragma unroll
        for (int ns = 0; ns < 4; ++ns)
          xbuf[row * XSTRIDE + (wn - 2) * 64 + ns * 16 + c] = hv[ms][ns][r];
      }
  }
  __syncthreads();  // x1 half-B visible; W2 chunk4 drained

#pragma unroll
  for (int kc = 4; kc < 8; ++kc) {
    gstep(acc2, (kc - 4) * 32);
    __syncthreads();
    if (kc < 7) {
      stage_chunk(32768 + (kc + 1) * 8192);
      __syncthreads();
    }
  }

  // ---------- LN2 + ReLU + dot(W3) + sigmoid ----------
  float w3v[4];
#pragma unroll
  for (int ns = 0; ns < 4; ++ns) {
    int n = bcol0 + ns * 16;
    bias[ns] = b2[n]; gg[ns] = g2[n]; bb[ns] = be2[n]; w3v[ns] = w3[n];
  }
#pragma unroll
  for (int ms = 0; ms < 4; ++ms) {
#pragma unroll
    for (int r = 0; r < 4; ++r) {
      float s = 0.f, sq = 0.f;
#pragma unroll
      for (int ns = 0; ns < 4; ++ns) {
        float v = acc2[ms][ns][r] + bias[ns];
        acc2[ms][ns][r] = v;
        s += v; sq += v * v;
      }
#pragma unroll
      for (int off = 1; off < 16; off <<= 1) {
        s += __shfl_xor(s, off, 64);
        sq += __shfl_xor(sq, off, 64);
      }
      if (c == 0) {
        int row = wm * 64 + ms * 16 + q * 4 + r;
        ssum[wn * 128 + row] = s;
        ssq[wn * 128 + row] = sq;
      }
    }
  }
  __syncthreads();
  if (t < 128) {
    float s = ssum[t] + ssum[128 + t] + ssum[256 + t] + ssum[384 + t];
    float sq = ssq[t] + ssq[128 + t] + ssq[256 + t] + ssq[384 + t];
    float mu = s * (1.f / 256.f);
    float var = sq * (1.f / 256.f) - mu * mu;
    smean[t] = mu;
    srstd[t] = rsqrtf(var + 1e-5f);
  }
  __syncthreads();
#pragma unroll
  for (int ms = 0; ms < 4; ++ms) {
#pragma unroll
    for (int r = 0; r < 4; ++r) {
      int row = wm * 64 + ms * 16 + q * 4 + r;
      float mu = smean[row], rs = srstd[row];
      float p = 0.f;
#pragma unroll
      for (int ns = 0; ns < 4; ++ns) {
        float v = (acc2[ms][ns][r] - mu) * rs * gg[ns] + bb[ns];
        v = fmaxf(v, 0.f);
        p = fmaf(v, w3v[ns], p);
      }
#pragma unroll
      for (int off = 1; off < 16; off <<= 1) p += __shfl_xor(p, off, 64);
      if (c == 0) ssum[wn * 128 + row] = p;
    }
  }
  __syncthreads();
  if (t < 128) {
    int e = ebase + t;
    if (e < E) {
      float sres = ssum[t] + ssum[128 + t] + ssum[256 + t] + ssum[384 + t] + b3[0];
      out[e] = 1.f / (1.f + __expf(-sres));
    }
  }
}

extern "C" void kernel_launch(void* const* d_in, const int* in_sizes, int n_in,
                              void* d_out, int out_size, void* d_ws, size_t ws_size,
                              hipStream_t stream) {
  const float* h = (const float*)d_in[0];
  const int* src = (const int*)d_in[1];   // harness delivers integer inputs as int32
  const int* dst = (const int*)d_in[2];
  const float* W1 = (const float*)d_in[3];
  const float* b1 = (const float*)d_in[4];
  const float* g1 = (const float*)d_in[5];
  const float* be1 = (const float*)d_in[6];
  const float* W2 = (const float*)d_in[7];
  const float* b2 = (const float*)d_in[8];
  const float* g2 = (const float*)d_in[9];
  const float* be2 = (const float*)d_in[10];
  const float* W3 = (const float*)d_in[11];
  const float* b3 = (const float*)d_in[12];
  float* out = (float*)d_out;
  const int E = in_sizes[1];
  const int nrows = in_sizes[0] / 128;
  f16_t* wks = (f16_t*)d_ws;  // needs 98304 f16 = 196608 bytes

  wconv<<<256, 256, 0, stream>>>(W1, W2, wks);
  const int tiles = (E + 127) / 128;
  fused_mlp<<<tiles, 512, 0, stream>>>(h, src, dst, wks, b1, g1, be1,
                                       b2, g2, be2, W3, b3, out, E, nrows);
}

// Round 3
// 466.159 us; speedup vs baseline: 1.6411x; 1.6411x over previous
//
#include <hip/hip_runtime.h>
#include <math.h>

typedef _Float16 f16_t;
typedef _Float16 f16x8 __attribute__((ext_vector_type(8)));
typedef _Float16 f16x4 __attribute__((ext_vector_type(4)));
typedef float f32x4 __attribute__((ext_vector_type(4)));

// Convert W1 [256][128] and W2 [256][256] fp32 -> fp16 into d_ws, k-chunk-major with
// a 16B-group swizzle baked in so a lane-linear global_load_lds copy yields
// conflict-free B-fragment ds_read_b128s.
// Chunk kc = [256 n][32 k] (8192 f16 = 16KB). Element (n, k=kc*32+q*8+j) stored at
// chunkBase + n*32 + (q ^ ((n>>1)&3))*8 + j.  W1: chunks 0..3 at 0; W2: chunks 0..7 at 32768.
__global__ void wconv(const float* __restrict__ W1, const float* __restrict__ W2,
                      f16_t* __restrict__ o) {
  int idx = blockIdx.x * 256 + threadIdx.x;  // 0..65535
  if (idx < 32768) {
    int n = idx >> 7, k = idx & 127;
    int kc = k >> 5, q = (k >> 3) & 3, j = k & 7;
    int qp = q ^ ((n >> 1) & 3);
    o[kc * 8192 + n * 32 + qp * 8 + j] = (f16_t)W1[idx];
  }
  {
    int n = idx >> 8, k = idx & 255;
    int kc = k >> 5, q = (k >> 3) & 3, j = k & 7;
    int qp = q ^ ((n >> 1) & 3);
    o[32768 + kc * 8192 + n * 32 + qp * 8 + j] = (f16_t)W2[idx];
  }
}

__device__ __forceinline__ void stage16(const f16_t* g, f16_t* l) {
  __builtin_amdgcn_global_load_lds(
      (const __attribute__((address_space(1))) void*)g,
      (__attribute__((address_space(3))) void*)l, 16, 0, 0);
}

// Fused: gather-product -> GEMM1+LN+ReLU -> GEMM2 (K-split) +LN+ReLU -> dot(W3)+sigmoid.
// 1024 threads = 16 waves as 4 wave-rows (M=32) x 4 wave-cols (N=64); M-tile 128 edges.
// xbuf: swizzled stride-128 f16 [128 rows][16 groups of 8]; group' = (k>>3) ^ (row&15).
// LN stats alias into xbuf (x is dead whenever stats are live).
// Static LDS = 32768 (xbuf) + 32768 (wb double buffer) = 65536 B.
__global__ __launch_bounds__(1024, 1) void fused_mlp(
    const float* __restrict__ h,
    const int* __restrict__ src,
    const int* __restrict__ dst,
    const f16_t* __restrict__ wks,
    const float* __restrict__ b1, const float* __restrict__ g1, const float* __restrict__ be1,
    const float* __restrict__ b2, const float* __restrict__ g2, const float* __restrict__ be2,
    const float* __restrict__ w3, const float* __restrict__ b3,
    float* __restrict__ out, int E, int nrows) {
  __shared__ __attribute__((aligned(16))) f16_t xbuf[128 * 128];
  __shared__ __attribute__((aligned(16))) f16_t wb[2 * 8192];
  float* ssum = (float*)xbuf;          // [512]
  float* ssq = (float*)xbuf + 512;     // [512]
  float* smean = (float*)xbuf + 1024;  // [128]
  float* srstd = (float*)xbuf + 1152;  // [128]

  const int t = threadIdx.x;
  const int ebase = blockIdx.x * 128;

  auto stage_chunk = [&](int dbuf, int srcOff) {  // 1024 thr x 16B = one 16KB chunk
    stage16(wks + srcOff + t * 8, wb + dbuf * 8192 + t * 8);
  };

  // W1 chunk 0 in flight while we gather
  stage_chunk(0, 0);

  // ---------- gather: x0[m][k] = h[src][k]*h[dst][k] (fp16, swizzled) ----------
  {
    const int m = t >> 3;
    const int kq = (t & 7) * 16;
    const int e = ebase + m;
    const int ga = ((kq >> 3)) ^ (m & 15);
    const int gb = ((kq >> 3) + 1) ^ (m & 15);
    f16_t* xrow = xbuf + m * 128;
    if (e < E) {
      int si = src[e], di = dst[e];
      si = ((unsigned)si < (unsigned)nrows) ? si : 0;
      di = ((unsigned)di < (unsigned)nrows) ? di : 0;
      const float* hs = h + (long long)si * 128 + kq;
      const float* hd = h + (long long)di * 128 + kq;
      const float4 a0 = *(const float4*)(hs);
      const float4 a1 = *(const float4*)(hs + 4);
      const float4 a2 = *(const float4*)(hs + 8);
      const float4 a3 = *(const float4*)(hs + 12);
      const float4 c0 = *(const float4*)(hd);
      const float4 c1 = *(const float4*)(hd + 4);
      const float4 c2 = *(const float4*)(hd + 8);
      const float4 c3 = *(const float4*)(hd + 12);
      f16x8 v0, v1;
      v0[0] = (f16_t)(a0.x * c0.x); v0[1] = (f16_t)(a0.y * c0.y);
      v0[2] = (f16_t)(a0.z * c0.z); v0[3] = (f16_t)(a0.w * c0.w);
      v0[4] = (f16_t)(a1.x * c1.x); v0[5] = (f16_t)(a1.y * c1.y);
      v0[6] = (f16_t)(a1.z * c1.z); v0[7] = (f16_t)(a1.w * c1.w);
      v1[0] = (f16_t)(a2.x * c2.x); v1[1] = (f16_t)(a2.y * c2.y);
      v1[2] = (f16_t)(a2.z * c2.z); v1[3] = (f16_t)(a2.w * c2.w);
      v1[4] = (f16_t)(a3.x * c3.x); v1[5] = (f16_t)(a3.y * c3.y);
      v1[6] = (f16_t)(a3.z * c3.z); v1[7] = (f16_t)(a3.w * c3.w);
      *(f16x8*)(xrow + ga * 8) = v0;
      *(f16x8*)(xrow + gb * 8) = v1;
    } else {
      f16x8 z = {};
      *(f16x8*)(xrow + ga * 8) = z;
      *(f16x8*)(xrow + gb * 8) = z;
    }
  }
  __syncthreads();  // x0 ready; W1 chunk0 drained

  const int lane = t & 63;
  const int wave = t >> 6;
  const int wm = wave >> 2;  // 0..3 (wave-row, 32 M each)
  const int wn = wave & 3;   // 0..3 (wave-col, 64 N each)
  const int c = lane & 15;
  const int q = lane >> 4;
  const int qc = q ^ c;                     // A-frag swizzle base
  const int qp = q ^ ((c >> 1) & 3);        // B-frag swizzle (matches wconv)
  const int arow0 = wm * 32 + c;
  const int bcol0 = wn * 64 + c;
  const int boff = bcol0 * 32 + qp * 8;     // + ns*512

  auto gstep = [&](f32x4 (&A)[2][4], int kc, int rbuf) {
    f16x8 af[2], bf[4];
    const int gq = (((kc << 2) ^ qc) << 3);
#pragma unroll
    for (int ms = 0; ms < 2; ++ms)
      af[ms] = *(const f16x8*)(xbuf + (arow0 + ms * 16) * 128 + gq);
#pragma unroll
    for (int ns = 0; ns < 4; ++ns)
      bf[ns] = *(const f16x8*)(wb + rbuf * 8192 + boff + ns * 512);
#pragma unroll
    for (int ms = 0; ms < 2; ++ms)
#pragma unroll
      for (int ns = 0; ns < 4; ++ns)
        A[ms][ns] = __builtin_amdgcn_mfma_f32_16x16x32_f16(af[ms], bf[ns], A[ms][ns], 0, 0, 0);
  };

  f32x4 acc[2][4];
#pragma unroll
  for (int ms = 0; ms < 2; ++ms)
#pragma unroll
    for (int ns = 0; ns < 4; ++ns) acc[ms][ns] = (f32x4){0.f, 0.f, 0.f, 0.f};

  // ---------- GEMM1: x0 @ W1^T -> [128,256]; prefetch overlapped ----------
#pragma unroll
  for (int kc = 0; kc < 4; ++kc) {
    stage_chunk((kc & 1) ^ 1, (kc < 3) ? (kc + 1) * 8192 : 32768);  // W1 c1..3, then W2 c0
    gstep(acc, kc, kc & 1);
    __syncthreads();  // readers done + staged chunk drained
  }

  // ---------- LN1 (stats live in xbuf; x0 dead) ----------
  float bias[4], gg[4], bb[4];
#pragma unroll
  for (int ns = 0; ns < 4; ++ns) {
    int n = bcol0 + ns * 16;
    bias[ns] = b1[n]; gg[ns] = g1[n]; bb[ns] = be1[n];
  }
#pragma unroll
  for (int ms = 0; ms < 2; ++ms) {
#pragma unroll
    for (int r = 0; r < 4; ++r) {
      float s = 0.f, sq = 0.f;
#pragma unroll
      for (int ns = 0; ns < 4; ++ns) {
        float v = acc[ms][ns][r] + bias[ns];
        acc[ms][ns][r] = v;
        s += v; sq += v * v;
      }
#pragma unroll
      for (int off = 1; off < 16; off <<= 1) {
        s += __shfl_xor(s, off, 64);
        sq += __shfl_xor(sq, off, 64);
      }
      if (c == 0) {
        int row = wm * 32 + ms * 16 + q * 4 + r;
        ssum[wn * 128 + row] = s;
        ssq[wn * 128 + row] = sq;
      }
    }
  }
  __syncthreads();
  if (t < 128) {
    float s = ssum[t] + ssum[128 + t] + ssum[256 + t] + ssum[384 + t];
    float sq = ssq[t] + ssq[128 + t] + ssq[256 + t] + ssq[384 + t];
    float mu = s * (1.f / 256.f);
    float var = sq * (1.f / 256.f) - mu * mu;
    smean[t] = mu;
    srstd[t] = rsqrtf(var + 1e-5f);
  }
  __syncthreads();

  // normalize + relu -> packed fp16 in regs (reads smean/srstd)
  f16x4 hv[2][4];
#pragma unroll
  for (int ms = 0; ms < 2; ++ms) {
#pragma unroll
    for (int r = 0; r < 4; ++r) {
      int row = wm * 32 + ms * 16 + q * 4 + r;
      float mu = smean[row], rs = srstd[row];
#pragma unroll
      for (int ns = 0; ns < 4; ++ns) {
        float v = (acc[ms][ns][r] - mu) * rs * gg[ns] + bb[ns];
        hv[ms][ns][r] = (f16_t)fmaxf(v, 0.f);
      }
    }
  }
  __syncthreads();  // stats fully consumed; xbuf now writable

  // x1 K-half A (cols 0..127), written by waves wn<2 (swizzled layout)
  if (wn < 2) {
    const int cb = wn * 8;
#pragma unroll
    for (int ms = 0; ms < 2; ++ms)
#pragma unroll
      for (int r = 0; r < 4; ++r) {
        const int row = wm * 32 + ms * 16 + q * 4 + r;
        const int rx = q * 4 + r;
        f16_t* xr = xbuf + row * 128 + (c & 7);
#pragma unroll
        for (int ns = 0; ns < 4; ++ns)
          xr[((cb + ns * 2 + (c >> 3)) ^ rx) << 3] = hv[ms][ns][r];
      }
  }
  __syncthreads();  // x1 half-A visible; W2 chunk0 resident (buf 0)

  // ---------- GEMM2 (K-split): pass A k=0..127, pass B k=128..255 ----------
  f32x4 acc2[2][4];
#pragma unroll
  for (int ms = 0; ms < 2; ++ms)
#pragma unroll
    for (int ns = 0; ns < 4; ++ns) acc2[ms][ns] = (f32x4){0.f, 0.f, 0.f, 0.f};

#pragma unroll
  for (int kc = 0; kc < 4; ++kc) {
    stage_chunk((kc & 1) ^ 1, 32768 + (kc + 1) * 8192);  // W2 c1..4
    gstep(acc2, kc, kc & 1);
    __syncthreads();
  }

  // x1 K-half B (cols 128..255 -> local 0..127), waves wn>=2
  if (wn >= 2) {
    const int cb = (wn - 2) * 8;
#pragma unroll
    for (int ms = 0; ms < 2; ++ms)
#pragma unroll
      for (int r = 0; r < 4; ++r) {
        const int row = wm * 32 + ms * 16 + q * 4 + r;
        const int rx = q * 4 + r;
        f16_t* xr = xbuf + row * 128 + (c & 7);
#pragma unroll
        for (int ns = 0; ns < 4; ++ns)
          xr[((cb + ns * 2 + (c >> 3)) ^ rx) << 3] = hv[ms][ns][r];
      }
  }
  __syncthreads();  // x1 half-B visible; W2 chunk4 resident (buf 0)

#pragma unroll
  for (int kc = 4; kc < 8; ++kc) {
    if (kc < 7) stage_chunk((kc & 1) ^ 1, 32768 + (kc + 1) * 8192);  // W2 c5..7
    gstep(acc2, kc - 4, kc & 1);
    __syncthreads();
  }

  // ---------- LN2 + ReLU + dot(W3) + sigmoid (stats alias xbuf; x1 dead) ----------
  float w3v[4];
#pragma unroll
  for (int ns = 0; ns < 4; ++ns) {
    int n = bcol0 + ns * 16;
    bias[ns] = b2[n]; gg[ns] = g2[n]; bb[ns] = be2[n]; w3v[ns] = w3[n];
  }
#pragma unroll
  for (int ms = 0; ms < 2; ++ms) {
#pragma unroll
    for (int r = 0; r < 4; ++r) {
      float s = 0.f, sq = 0.f;
#pragma unroll
      for (int ns = 0; ns < 4; ++ns) {
        float v = acc2[ms][ns][r] + bias[ns];
        acc2[ms][ns][r] = v;
        s += v; sq += v * v;
      }
#pragma unroll
      for (int off = 1; off < 16; off <<= 1) {
        s += __shfl_xor(s, off, 64);
        sq += __shfl_xor(sq, off, 64);
      }
      if (c == 0) {
        int row = wm * 32 + ms * 16 + q * 4 + r;
        ssum[wn * 128 + row] = s;
        ssq[wn * 128 + row] = sq;
      }
    }
  }
  __syncthreads();
  if (t < 128) {
    float s = ssum[t] + ssum[128 + t] + ssum[256 + t] + ssum[384 + t];
    float sq = ssq[t] + ssq[128 + t] + ssq[256 + t] + ssq[384 + t];
    float mu = s * (1.f / 256.f);
    float var = sq * (1.f / 256.f) - mu * mu;
    smean[t] = mu;
    srstd[t] = rsqrtf(var + 1e-5f);
  }
  __syncthreads();
#pragma unroll
  for (int ms = 0; ms < 2; ++ms) {
#pragma unroll
    for (int r = 0; r < 4; ++r) {
      int row = wm * 32 + ms * 16 + q * 4 + r;
      float mu = smean[row], rs = srstd[row];
      float p = 0.f;
#pragma unroll
      for (int ns = 0; ns < 4; ++ns) {
        float v = (acc2[ms][ns][r] - mu) * rs * gg[ns] + bb[ns];
        v = fmaxf(v, 0.f);
        p = fmaf(v, w3v[ns], p);
      }
#pragma unroll
      for (int off = 1; off < 16; off <<= 1) p += __shfl_xor(p, off, 64);
      if (c == 0) ssum[wn * 128 + row] = p;  // disjoint from smean/srstd
    }
  }
  __syncthreads();
  if (t < 128) {
    int e = ebase + t;
    if (e < E) {
      float sres = ssum[t] + ssum[128 + t] + ssum[256 + t] + ssum[384 + t] + b3[0];
      out[e] = 1.f / (1.f + __expf(-sres));
    }
  }
}

extern "C" void kernel_launch(void* const* d_in, const int* in_sizes, int n_in,
                              void* d_out, int out_size, void* d_ws, size_t ws_size,
                              hipStream_t stream) {
  const float* h = (const float*)d_in[0];
  const int* src = (const int*)d_in[1];
  const int* dst = (const int*)d_in[2];
  const float* W1 = (const float*)d_in[3];
  const float* b1 = (const float*)d_in[4];
  const float* g1 = (const float*)d_in[5];
  const float* be1 = (const float*)d_in[6];
  const float* W2 = (const float*)d_in[7];
  const float* b2 = (const float*)d_in[8];
  const float* g2 = (const float*)d_in[9];
  const float* be2 = (const float*)d_in[10];
  const float* W3 = (const float*)d_in[11];
  const float* b3 = (const float*)d_in[12];
  float* out = (float*)d_out;
  const int E = in_sizes[1];
  const int nrows = in_sizes[0] / 128;
  f16_t* wks = (f16_t*)d_ws;  // 98304 f16 = 196608 bytes

  wconv<<<256, 256, 0, stream>>>(W1, W2, wks);
  const int tiles = (E + 127) / 128;
  fused_mlp<<<tiles, 1024, 0, stream>>>(h, src, dst, wks, b1, g1, be1,
                                        b2, g2, be2, W3, b3, out, E, nrows);
}